// Round 8
// baseline (114.625 us; speedup 1.0000x reference)
//
#include <hip/hip_runtime.h>

// Problem constants
#define Bc  32
#define Nc  16
#define Tc  64
#define Hc  256
#define NTc 1024   // N*T

typedef unsigned short u16;
using v8s = __attribute__((ext_vector_type(8))) short;   // 8 bf16 = 4 VGPRs (MFMA A/B frag)
using v4f = __attribute__((ext_vector_type(4))) float;   // MFMA C/D frag

// fp32 -> bf16 round-to-nearest-even (inputs finite)
static __device__ __forceinline__ u16 f2bf(float x) {
    unsigned u = __float_as_uint(x);
    unsigned r = u + 0x7fffu + ((u >> 16) & 1u);
    return (u16)(r >> 16);
}
static __device__ __forceinline__ float bf2f(u16 h) {
    return __uint_as_float(((unsigned)h) << 16);
}

// ws layout (u16 units):
//  XH [B][N][T][H] bf16 hi of neigh (row-major)        16.7 MB
//  XL [B][N][T][H] bf16 lo                              16.7 MB
//  NODEf [B][4096 frags][8]: f<2048 = node-hi frag-major, f>=2048 = node-lo
//        frag f=(nt*8+ksb)*64+lane holds node[t=nt*16+c][h=ksb*32+quad*8+j]
//  MTf   [B][2048 frags][8]: f=(ht*2+ktb)*64+lane holds M[t=ktb*32+quad*8+j][h=ht*16+c]
//  Wsum  [B][T] fp32
#define XSZ   ((size_t)Bc * Nc * Tc * Hc)
#define NODEF_SZ ((size_t)Bc * 4096 * 8)
#define MTF_SZ   ((size_t)Bc * 2048 * 8)

// ---------------------------------------------------------------------------
// Prep kernel, 544 blocks:
//  blocks [0,512): (b, hc in [0,8), ktb in [0,2)): 32t x 32h tile.
//    - read neigh for all 16 i (128 B-coalesced rows), sum -> mean
//    - emit XH/XL bf16 hi/lo per element (row-major)
//    - LDS-transpose mean -> 128 MTf frags
//  blocks [512,544): node hi/lo split -> NODEf frag-major; zero Wsum.
// ---------------------------------------------------------------------------
__global__ __launch_bounds__(256) void prep_kernel(const float* __restrict__ neigh,
                                                   const float* __restrict__ node,
                                                   u16* __restrict__ XH,
                                                   u16* __restrict__ XL,
                                                   u16* __restrict__ NODEf,
                                                   u16* __restrict__ MTf,
                                                   float* __restrict__ Wsum) {
    __shared__ float Ls[32][33];
    int bk = blockIdx.x, tid = threadIdx.x;

    if (bk < 512) {
        int b   = bk >> 4;
        int hc  = (bk >> 1) & 7;
        int ktb = bk & 1;
        int t0  = ktb * 32;
        int h0  = hc * 32;
        int t_l = tid >> 3;        // 0..31
        int h8  = tid & 7;         // float4 index within 32-h chunk
        float4 a = make_float4(0.f, 0.f, 0.f, 0.f);
#pragma unroll
        for (int i = 0; i < Nc; i++) {
            size_t off = ((size_t)((b * Nc + i) * Tc) + t0 + t_l) * Hc + h0 + h8 * 4;
            float4 v = *(const float4*)(neigh + off);
            a.x += v.x; a.y += v.y; a.z += v.z; a.w += v.w;
            ushort4 hs, ls;
            hs.x = f2bf(v.x); ls.x = f2bf(v.x - bf2f(hs.x));
            hs.y = f2bf(v.y); ls.y = f2bf(v.y - bf2f(hs.y));
            hs.z = f2bf(v.z); ls.z = f2bf(v.z - bf2f(hs.z));
            hs.w = f2bf(v.w); ls.w = f2bf(v.w - bf2f(hs.w));
            *(ushort4*)(XH + off) = hs;
            *(ushort4*)(XL + off) = ls;
        }
        const float r = 1.0f / 16.0f;
        Ls[t_l][h8 * 4 + 0] = a.x * r;
        Ls[t_l][h8 * 4 + 1] = a.y * r;
        Ls[t_l][h8 * 4 + 2] = a.z * r;
        Ls[t_l][h8 * 4 + 3] = a.w * r;
        __syncthreads();
        if (tid < 128) {
            int htl  = tid >> 6;                // 0..1 -> ht = hc*2 + htl
            int lane = tid & 63;
            int quad = lane >> 4;
            int c    = lane & 15;
            v8s o;
#pragma unroll
            for (int j = 0; j < 8; j++)
                o[j] = (short)f2bf(Ls[quad * 8 + j][htl * 16 + c]);
            int ht = hc * 2 + htl;
            *(v8s*)(MTf + ((size_t)b * 2048 + (ht * 2 + ktb) * 64 + lane) * 8) = o;
        }
    } else {
        int b = bk - 512;
#pragma unroll
        for (int rep = 0; rep < 8; rep++) {
            int f    = rep * 256 + tid;       // 0..2047
            int nt   = f >> 9;
            int ksb  = (f >> 6) & 7;
            int lane = f & 63;
            int quad = lane >> 4;
            int c    = lane & 15;
            const float* src = node + ((size_t)b * Tc + nt * 16 + c) * Hc + ksb * 32 + quad * 8;
            float4 f0 = *(const float4*)(src);
            float4 f1 = *(const float4*)(src + 4);
            v8s hs, ls;
            float vin[8] = {f0.x, f0.y, f0.z, f0.w, f1.x, f1.y, f1.z, f1.w};
#pragma unroll
            for (int j = 0; j < 8; j++) {
                u16 h = f2bf(vin[j]);
                hs[j] = (short)h;
                ls[j] = (short)f2bf(vin[j] - bf2f(h));
            }
            *(v8s*)(NODEf + ((size_t)b * 4096 + f) * 8)        = hs;   // hi
            *(v8s*)(NODEf + ((size_t)b * 4096 + 2048 + f) * 8) = ls;   // lo
        }
        if (tid < 64) Wsum[b * 64 + tid] = 0.f;
    }
}

// ---------------------------------------------------------------------------
// Fused MFMA kernel: block = (b, i), 4 waves, 3 barriers, all B-streams LDS.
//  Stage node hi+lo frags (64 KB, one copy) -> barrier.
//  Phase A: A-frags = 2 v8s direct loads from prep-split XH/XL (lane-private
//    row, zero VALU); B-frags from LDS.  3 MFMAs (hh+hl+lh) per (nt,ksb).
//  Softmax in C-layout regs; column sums -> Wsum atomics;
//  P C->A transpose via wave-private LDS band (no barrier).
//  barrier -> stage MTf (32 KB, reusing node LDS) -> barrier ->
//  Phase B: out = P @ M with B-frags from LDS; C-layout scalar stores.
// Frag layouts (m89/m97-verified): A/B (m|n)=lane&15, k=quad*8+j;
//                                  C/D col=lane&15, row=quad*4+reg.
// LDS = 64 KB Bs + 9.2 KB Ph = 73.2 KB -> 2 blocks/CU (8 waves).
// ---------------------------------------------------------------------------
__global__ __launch_bounds__(256) void fused_kernel(const u16* __restrict__ XH,
                                                    const u16* __restrict__ XL,
                                                    const u16* __restrict__ NODEf,
                                                    const u16* __restrict__ MTf,
                                                    const int* __restrict__ nbr,
                                                    float* __restrict__ out,
                                                    float* __restrict__ Wsum) {
    __shared__ __align__(16) u16 Bs[4096 * 8];   // 64 KB; Phase B reuses first 32 KB
    __shared__ u16 Ph[64][72];

    int b  = blockIdx.x >> 4;
    int i  = blockIdx.x & 15;
    int q0 = i << 6;

    int tid  = threadIdx.x;
    int w    = tid >> 6;
    int lane = tid & 63;
    int quad = lane >> 4;
    int c    = lane & 15;

    // neighbors_number: int64 per reference; harness may upload int32.
    // Values in [1,16] so nbr[1]==0 <=> int64 (high word of elem 0).
    int nb = (nbr[1] == 0) ? nbr[2 * b] : nbr[b];
    float rscale = rsqrtf((float)nb);

    // ---- Stage node hi+lo frags into LDS (one 64 KB cooperative copy) ----
    const u16* NFb = NODEf + (size_t)b * 4096 * 8;
#pragma unroll
    for (int rep = 0; rep < 16; rep++) {
        int ch = rep * 256 + tid;             // 4096 x 16 B
        *(uint4*)&Bs[ch * 8] = *(const uint4*)(NFb + ch * 8);
    }
    __syncthreads();   // barrier 1

    size_t xoff = ((size_t)((b * Nc + i) * Tc) + w * 16 + c) * Hc;
    const u16* XHrow = XH + xoff;
    const u16* XLrow = XL + xoff;

    v4f acc[4];
#pragma unroll
    for (int nt = 0; nt < 4; nt++)
#pragma unroll
        for (int rg = 0; rg < 4; rg++) acc[nt][rg] = 0.f;

    // ---- Phase A: K=256, 8 k-steps of 32; zero VALU in loop ----
#pragma unroll
    for (int ksb = 0; ksb < 8; ksb++) {
        v8s ah = *(const v8s*)(XHrow + ksb * 32 + quad * 8);
        v8s al = *(const v8s*)(XLrow + ksb * 32 + quad * 8);
#pragma unroll
        for (int nt = 0; nt < 4; nt++) {
            int f = (nt * 8 + ksb) * 64 + lane;
            v8s bh = *(const v8s*)&Bs[f * 8];
            v8s bl = *(const v8s*)&Bs[(f + 2048) * 8];
            acc[nt] = __builtin_amdgcn_mfma_f32_16x16x32_bf16(ah, bh, acc[nt], 0, 0, 0);
            acc[nt] = __builtin_amdgcn_mfma_f32_16x16x32_bf16(ah, bl, acc[nt], 0, 0, 0);
            acc[nt] = __builtin_amdgcn_mfma_f32_16x16x32_bf16(al, bh, acc[nt], 0, 0, 0);
        }
    }

    // ---- Softmax over t (C-layout: col = nt*16+c, row = w*16+quad*4+rg) ----
#pragma unroll
    for (int nt = 0; nt < 4; nt++)
#pragma unroll
        for (int rg = 0; rg < 4; rg++) acc[nt][rg] *= rscale;

#pragma unroll
    for (int rg = 0; rg < 4; rg++) {
        float m = fmaxf(fmaxf(acc[0][rg], acc[1][rg]), fmaxf(acc[2][rg], acc[3][rg]));
#pragma unroll
        for (int d = 1; d < 16; d <<= 1) m = fmaxf(m, __shfl_xor(m, d));
        float e0 = __expf(acc[0][rg] - m);
        float e1 = __expf(acc[1][rg] - m);
        float e2 = __expf(acc[2][rg] - m);
        float e3 = __expf(acc[3][rg] - m);
        float s = e0 + e1 + e2 + e3;
#pragma unroll
        for (int d = 1; d < 16; d <<= 1) s += __shfl_xor(s, d);
        float inv = 1.0f / s;
        acc[0][rg] = e0 * inv; acc[1][rg] = e1 * inv;
        acc[2][rg] = e2 * inv; acc[3][rg] = e3 * inv;
    }

    // Column sums -> global atomics (per wave, fire-and-forget).
#pragma unroll
    for (int nt = 0; nt < 4; nt++) {
        float cs = acc[nt][0] + acc[nt][1] + acc[nt][2] + acc[nt][3];
        cs += __shfl_xor(cs, 16);
        cs += __shfl_xor(cs, 32);
        if (quad == 0) atomicAdd(&Wsum[b * Tc + nt * 16 + c], cs);
    }

    // P -> wave-private LDS band (C->A transpose, intra-wave)
#pragma unroll
    for (int nt = 0; nt < 4; nt++)
#pragma unroll
        for (int rg = 0; rg < 4; rg++)
            Ph[w * 16 + quad * 4 + rg][nt * 16 + c] = f2bf(acc[nt][rg]);

    v8s pa0 = *(const v8s*)&Ph[w * 16 + c][quad * 8];
    v8s pa1 = *(const v8s*)&Ph[w * 16 + c][32 + quad * 8];

    __syncthreads();   // barrier 2: all Phase A reads of Bs done

    // ---- Stage MTf (32 KB) into the reused LDS region ----
    const u16* MTb = MTf + (size_t)b * 2048 * 8;
#pragma unroll
    for (int rep = 0; rep < 8; rep++) {
        int ch = rep * 256 + tid;             // 2048 x 16 B
        *(uint4*)&Bs[ch * 8] = *(const uint4*)(MTb + ch * 8);
    }
    __syncthreads();   // barrier 3

    // ---- Phase B: out = P(64x64) @ M(64x256); B-frags from LDS ----
    float* ob = out + ((size_t)b * NTc + q0 + w * 16 + quad * 4) * Hc + c;
#pragma unroll
    for (int ht = 0; ht < 16; ht++) {
        v8s b0 = *(const v8s*)&Bs[((ht * 2 + 0) * 64 + lane) * 8];
        v8s b1 = *(const v8s*)&Bs[((ht * 2 + 1) * 64 + lane) * 8];
        v4f oc;
        oc[0] = 0.f; oc[1] = 0.f; oc[2] = 0.f; oc[3] = 0.f;
        oc = __builtin_amdgcn_mfma_f32_16x16x32_bf16(pa0, b0, oc, 0, 0, 0);
        oc = __builtin_amdgcn_mfma_f32_16x16x32_bf16(pa1, b1, oc, 0, 0, 0);
#pragma unroll
        for (int rg = 0; rg < 4; rg++)
            ob[(size_t)rg * Hc + ht * 16] = oc[rg];
    }
}

// ---------------------------------------------------------------------------
// W[b,i,t] = Wsum[b,t] / 16  (independent of i)
// ---------------------------------------------------------------------------
__global__ __launch_bounds__(256) void wexp_kernel(const float* __restrict__ Wsum,
                                                   float* __restrict__ Wout) {
    int idx = blockIdx.x * 256 + threadIdx.x;   // over B*N*T = 32768
    int b = idx >> 10;
    int t = idx & 63;
    Wout[idx] = Wsum[b * Tc + t] * (1.0f / 16.0f);
}

// ---------------------------------------------------------------------------
extern "C" void kernel_launch(void* const* d_in, const int* in_sizes, int n_in,
                              void* d_out, int out_size, void* d_ws, size_t ws_size,
                              hipStream_t stream) {
    const float* node  = (const float*)d_in[0];   // (B,T,H)
    const float* neigh = (const float*)d_in[1];   // (B,N,T,H)
    const int*   nbr   = (const int*)d_in[2];     // (B,) int32/int64 (detected)

    float* out = (float*)d_out;                   // (B,NT,H) then W (B,N,T)

    u16* XHw = (u16*)d_ws;
    u16* XLw = XHw + XSZ;
    u16* NFw = XLw + XSZ;
    u16* MTw = NFw + NODEF_SZ;
    float* Ww = (float*)(MTw + MTF_SZ);

    prep_kernel <<<544, 256, 0, stream>>>(neigh, node, XHw, XLw, NFw, MTw, Ww);
    fused_kernel<<<512, 256, 0, stream>>>(XHw, XLw, NFw, MTw, nbr, out, Ww);
    wexp_kernel <<<128, 256, 0, stream>>>(Ww, out + (size_t)Bc * NTc * Hc);
}